// Round 2
// baseline (363.395 us; speedup 1.0000x reference)
//
#include <hip/hip_runtime.h>

// e3nn fully-connected tensor product, v5: f16 MFMA 32x32x16, barrier-free.
// One wave owns 32 rows (lane&31 = its row). x1/x2 features live in registers
// (loaded once, coalesced float4). B-fragments are loaded DIRECTLY from global
// (wsW, 320 KB, L2-resident) into registers: lane's fragment is a contiguous
// 16 B chunk -> perfectly coalesced global_load_dwordx4, L1/L2-served.
// No LDS, no __syncthreads, no global_load_lds: the compiler is free to
// software-pipeline loads across the fully-unrolled passes, and waves run
// desynchronized so MFMA and VALU co-issue across waves.

typedef _Float16 f16;
typedef f16 f16x8 __attribute__((ext_vector_type(8)));
typedef float f32x16 __attribute__((ext_vector_type(16)));

#define MFMA32(a, b, c) __builtin_amdgcn_mfma_f32_32x32x16_f16(a, b, c, 0, 0, 0)

// A000 = A011 = A101 = A111 = 1/sqrt(2048); A110 = 1/sqrt(6144)
#define SC_COMMON 0.022097086912079608f
#define SC_110    0.012757759118834242f

// ---------------- weight prep ------------------------------------------------
// ws order: c0=w000, c1=w110, c2=w011, c3=w101, c4=w111 (scales folded).
// B-frag (32x32x16): lane holds B[k=(lane>>5)*8+j][n=lane&31], K-chunk vh.
// idx = ((c*32 + u)*2 + vh)*512 + lane*8 + j
//   element = sc * W[u][ v = vh*16 + (lane>>5)*8 + j ][ w = lane&31 ]
__global__ void prep_w(const float* __restrict__ w000, const float* __restrict__ w011,
                       const float* __restrict__ w101, const float* __restrict__ w110,
                       const float* __restrict__ w111, f16* __restrict__ wsW)
{
    int flat = blockIdx.x * 256 + threadIdx.x;
    if (flat >= 5 * 32768) return;
    int c    = flat >> 15;
    int r    = flat & 32767;
    int j    = r & 7;
    int lane = (r >> 3) & 63;
    int vh   = (r >> 9) & 1;
    int u    = r >> 10;
    int v = vh * 16 + ((lane >> 5) << 3) + j;
    int w = lane & 31;
    const float* src; float sc;
    switch (c) {
        case 0: src = w000; sc = SC_COMMON; break;
        case 1: src = w110; sc = SC_110;    break;
        case 2: src = w011; sc = SC_COMMON; break;
        case 3: src = w101; sc = SC_COMMON; break;
        default: src = w111; sc = SC_COMMON; break;
    }
    wsW[flat] = (f16)(sc * src[u * 1024 + v * 32 + w]);
}

// ---------------- main kernel ------------------------------------------------
// MODE: 0 = w000 (s*s), 1 = w110 (vec dot), 2 = w011 (p011, 3 acc),
//       3 = w101 (p101, 3 acc), 4 = w111 (cross, 3 acc)
template <int MODE, int NA>
__device__ __forceinline__ void do_pass(f32x16 (&acc)[NA],
                                        const f16* __restrict__ wsrc,  // wsW + c*32768
                                        const f16x8 (&f1g)[4][4],
                                        const f16x8 (&f2g)[4][2], int lane)
{
#pragma unroll
    for (int u = 0; u < 32; ++u) {
#pragma unroll
        for (int vh = 0; vh < 2; ++vh) {
            f16x8 b = *(const f16x8*)(wsrc + u * 1024 + vh * 512 + lane * 8);
            if (MODE == 0) {
                f16x8 a = f1g[0][u >> 3][u & 7] * f2g[0][vh];
                acc[0] = MFMA32(a, b, acc[0]);
            } else if (MODE == 1) {
                f16x8 a = f1g[1][u >> 3][u & 7] * f2g[1][vh];
                a += f1g[2][u >> 3][u & 7] * f2g[2][vh];
                a += f1g[3][u >> 3][u & 7] * f2g[3][vh];
                acc[0] = MFMA32(a, b, acc[0]);
            } else if (MODE == 2) {
#pragma unroll
                for (int j = 0; j < 3; ++j) {
                    f16x8 a = f1g[0][u >> 3][u & 7] * f2g[1 + j][vh];
                    acc[j] = MFMA32(a, b, acc[j]);
                }
            } else if (MODE == 3) {
#pragma unroll
                for (int j = 0; j < 3; ++j) {
                    f16x8 a = f1g[1 + j][u >> 3][u & 7] * f2g[0][vh];
                    acc[j] = MFMA32(a, b, acc[j]);
                }
            } else {
                // cross: k0:(i=1,j=2)->arrs(2,3); k1:(2,0)->(3,1); k2:(0,1)->(1,2)
#pragma unroll
                for (int k = 0; k < 3; ++k) {
                    const int P = (k == 0) ? 2 : (k == 1) ? 3 : 1;
                    const int Q = (k == 0) ? 3 : (k == 1) ? 1 : 2;
                    f16x8 a = f1g[P][u >> 3][u & 7] * f2g[Q][vh]
                            - f1g[Q][u >> 3][u & 7] * f2g[P][vh];
                    acc[k] = MFMA32(a, b, acc[k]);
                }
            }
        }
    }
}

__global__ __launch_bounds__(256, 2)
void tp_main(const float* __restrict__ x1, const float* __restrict__ x2,
             const f16* __restrict__ wsW, float* __restrict__ out)
{
    const int tid = threadIdx.x, lane = tid & 63, wv = tid >> 6;
    const int rowBase = blockIdx.x * 128 + wv * 32;
    const int mrow = lane & 31;          // this lane's row (A and C/D)
    const int half = lane >> 5;          // k-group
    const int klo = half * 8;
    const float4* x1r4 = (const float4*)(x1 + (size_t)(rowBase + mrow) * 128);
    const float4* x2r4 = (const float4*)(x2 + (size_t)(rowBase + mrow) * 128);

    // ---- f1: all 128 features of my row, f16, [arr][u] ----
    f16x8 f1g[4][4];
    {
        float b0[32];
#pragma unroll
        for (int g = 0; g < 8; ++g) ((float4*)b0)[g] = x1r4[g];
#pragma unroll
        for (int g = 0; g < 4; ++g)
#pragma unroll
            for (int j = 0; j < 8; ++j) f1g[0][g][j] = (f16)b0[g * 8 + j];
        float b1[96];
#pragma unroll
        for (int g = 0; g < 24; ++g) ((float4*)b1)[g] = x1r4[8 + g];
#pragma unroll
        for (int i = 0; i < 3; ++i)
#pragma unroll
            for (int g = 0; g < 4; ++g)
#pragma unroll
                for (int j = 0; j < 8; ++j)
                    f1g[1 + i][g][j] = (f16)b1[3 * (g * 8 + j) + i];
    }

    // ---- f2: my row's k-slice: v = vh*16 + klo + j, [arr][vh] ----
    f16x8 f2g[4][2];
    {
        float c0[16];
#pragma unroll
        for (int g = 0; g < 2; ++g) ((float4*)c0)[g]     = x2r4[klo / 4 + g];
#pragma unroll
        for (int g = 0; g < 2; ++g) ((float4*)c0)[2 + g] = x2r4[4 + klo / 4 + g];
#pragma unroll
        for (int vh = 0; vh < 2; ++vh)
#pragma unroll
            for (int j = 0; j < 8; ++j) f2g[0][vh][j] = (f16)c0[vh * 8 + j];
        // vec spans: floats [32+3*klo, +24) and [80+3*klo, +24), both 16B-aligned
        float c1[48];
        const int base1 = (32 + 3 * klo) / 4;
#pragma unroll
        for (int g = 0; g < 6; ++g) ((float4*)c1)[g]     = x2r4[base1 + g];
#pragma unroll
        for (int g = 0; g < 6; ++g) ((float4*)c1)[6 + g] = x2r4[base1 + 12 + g];
#pragma unroll
        for (int i = 0; i < 3; ++i)
#pragma unroll
            for (int vh = 0; vh < 2; ++vh)
#pragma unroll
                for (int j = 0; j < 8; ++j)
                    f2g[1 + i][vh][j] = (f16)c1[vh * 24 + 3 * j + i];
    }

    // ================= out0: w000 + w110 =================
    {
        f32x16 acc[1] = {};
        do_pass<0>(acc, wsW + 0 * 32768, f1g, f2g, lane);
        do_pass<1>(acc, wsW + 1 * 32768, f1g, f2g, lane);
#pragma unroll
        for (int reg = 0; reg < 16; ++reg) {
            int r = (reg & 3) + 8 * (reg >> 2) + 4 * half;
            out[(size_t)(rowBase + r) * 224 + mrow] = acc[0][reg];
        }
    }
    // ================= out1: w011 (p011) + w101 (p101) =================
    {
        f32x16 acc[3] = {};
        do_pass<2>(acc, wsW + 2 * 32768, f1g, f2g, lane);
        do_pass<3>(acc, wsW + 3 * 32768, f1g, f2g, lane);
#pragma unroll
        for (int reg = 0; reg < 16; ++reg) {
            int r = (reg & 3) + 8 * (reg >> 2) + 4 * half;
            size_t base = (size_t)(rowBase + r) * 224 + 32 + 3 * mrow;
            out[base + 0] = acc[0][reg];
            out[base + 1] = acc[1][reg];
            out[base + 2] = acc[2][reg];
        }
    }
    // ================= out2: w111 (cross) =================
    {
        f32x16 acc[3] = {};
        do_pass<4>(acc, wsW + 4 * 32768, f1g, f2g, lane);
#pragma unroll
        for (int reg = 0; reg < 16; ++reg) {
            int r = (reg & 3) + 8 * (reg >> 2) + 4 * half;
            size_t base = (size_t)(rowBase + r) * 224 + 128 + 3 * mrow;
            out[base + 0] = acc[0][reg];
            out[base + 1] = acc[1][reg];
            out[base + 2] = acc[2][reg];
        }
    }
}

// ---------------- launch -----------------------------------------------------
extern "C" void kernel_launch(void* const* d_in, const int* in_sizes, int n_in,
                              void* d_out, int out_size, void* d_ws, size_t ws_size,
                              hipStream_t stream)
{
    const float* x1   = (const float*)d_in[0];
    const float* x2   = (const float*)d_in[1];
    const float* w000 = (const float*)d_in[2];
    const float* w011 = (const float*)d_in[3];
    const float* w101 = (const float*)d_in[4];
    const float* w110 = (const float*)d_in[5];
    const float* w111 = (const float*)d_in[6];
    float* out = (float*)d_out;
    f16* wsW = (f16*)d_ws;  // 5 * 32768 f16 = 320 KB

    hipLaunchKernelGGL(prep_w, dim3(640), dim3(256), 0, stream,
                       w000, w011, w101, w110, w111, wsW);

    int n = in_sizes[0] / 128;  // 131072 rows
    hipLaunchKernelGGL(tp_main, dim3(n / 128), dim3(256), 0, stream,
                       x1, x2, wsW, out);
}

// Round 3
// 326.321 us; speedup vs baseline: 1.1136x; 1.1136x over previous
//
#include <hip/hip_runtime.h>

// e3nn fully-connected tensor product, v6: f16 MFMA 32x32x16, 3-buffer LDS
// ring with counted vmcnt (T3/T4) + setprio (T5) + 3 waves/SIMD target.
// One wave owns 32 rows (lane&31 = its row). x1/x2 features live in registers.
// Weights staged in 16 KB stages (8 u of one tensor), 20 stages total,
// prefetched 2 ahead into a 3-buffer ring. Per stage:
//   s_waitcnt vmcnt(4)   <- waits only loads issued 2 stages ago (landed)
//   s_barrier            <- all waves' loads for this stage landed
//   issue(s+2)           <- after barrier: WAR-safe (buffer last read s-1,
//                           reads consumed before top-of-s barrier)
//   setprio(1); 16 ds_read_b128 + MFMA cluster; setprio(0)
// No full vmcnt drain in steady state (v4 drained the just-issued prefetch
// at every __syncthreads -> the ~40% idle the counters showed).

typedef _Float16 f16;
typedef f16 f16x8 __attribute__((ext_vector_type(8)));
typedef float f32x16 __attribute__((ext_vector_type(16)));

#define MFMA32(a, b, c) __builtin_amdgcn_mfma_f32_32x32x16_f16(a, b, c, 0, 0, 0)

// A000 = A011 = A101 = A111 = 1/sqrt(2048); A110 = 1/sqrt(6144)
#define SC_COMMON 0.022097086912079608f
#define SC_110    0.012757759118834242f

// ---------------- weight prep ------------------------------------------------
// ws order: c0=w000, c1=w110, c2=w011, c3=w101, c4=w111 (scales folded).
// B-frag (32x32x16): lane holds B[k=(lane>>5)*8+j][n=lane&31], K-chunk vh.
// idx = ((c*32 + u)*2 + vh)*512 + lane*8 + j
//   element = sc * W[u][ v = vh*16 + (lane>>5)*8 + j ][ w = lane&31 ]
__global__ void prep_w(const float* __restrict__ w000, const float* __restrict__ w011,
                       const float* __restrict__ w101, const float* __restrict__ w110,
                       const float* __restrict__ w111, f16* __restrict__ wsW)
{
    int flat = blockIdx.x * 256 + threadIdx.x;
    if (flat >= 5 * 32768) return;
    int c    = flat >> 15;
    int r    = flat & 32767;
    int j    = r & 7;
    int lane = (r >> 3) & 63;
    int vh   = (r >> 9) & 1;
    int u    = r >> 10;
    int v = vh * 16 + ((lane >> 5) << 3) + j;
    int w = lane & 31;
    const float* src; float sc;
    switch (c) {
        case 0: src = w000; sc = SC_COMMON; break;
        case 1: src = w110; sc = SC_110;    break;
        case 2: src = w011; sc = SC_COMMON; break;
        case 3: src = w101; sc = SC_COMMON; break;
        default: src = w111; sc = SC_COMMON; break;
    }
    wsW[flat] = (f16)(sc * src[u * 1024 + v * 32 + w]);
}

// ---------------- stage compute ---------------------------------------------
// One stage = 8 u-values (quarter Q of a tensor) x 2 vh chunks.
// MODE: 0 = w000 (s*s), 1 = w110 (vec dot), 2 = w011 (p011, 3 acc),
//       3 = w101 (p101, 3 acc), 4 = w111 (cross, 3 acc)
template <int Q, int MODE, int NA>
__device__ __forceinline__ void do_stage(f32x16 (&acc)[NA],
                                         const f16* __restrict__ ldsW,
                                         const f16x8 (&f1g)[4][4],
                                         const f16x8 (&f2g)[4][2], int lane)
{
#pragma unroll
    for (int ul = 0; ul < 8; ++ul) {
#pragma unroll
        for (int vh = 0; vh < 2; ++vh) {
            f16x8 b = *(const f16x8*)(ldsW + ul * 1024 + vh * 512 + lane * 8);
            if (MODE == 0) {
                f16x8 a = f1g[0][Q][ul] * f2g[0][vh];
                acc[0] = MFMA32(a, b, acc[0]);
            } else if (MODE == 1) {
                f16x8 a = f1g[1][Q][ul] * f2g[1][vh];
                a += f1g[2][Q][ul] * f2g[2][vh];
                a += f1g[3][Q][ul] * f2g[3][vh];
                acc[0] = MFMA32(a, b, acc[0]);
            } else if (MODE == 2) {
#pragma unroll
                for (int j = 0; j < 3; ++j) {
                    f16x8 a = f1g[0][Q][ul] * f2g[1 + j][vh];
                    acc[j] = MFMA32(a, b, acc[j]);
                }
            } else if (MODE == 3) {
#pragma unroll
                for (int j = 0; j < 3; ++j) {
                    f16x8 a = f1g[1 + j][Q][ul] * f2g[0][vh];
                    acc[j] = MFMA32(a, b, acc[j]);
                }
            } else {
                // cross: k0:(i=1,j=2)->arrs(2,3); k1:(2,0)->(3,1); k2:(0,1)->(1,2)
#pragma unroll
                for (int k = 0; k < 3; ++k) {
                    const int P = (k == 0) ? 2 : (k == 1) ? 3 : 1;
                    const int Q2 = (k == 0) ? 3 : (k == 1) ? 1 : 2;
                    f16x8 a = f1g[P][Q][ul] * f2g[Q2][vh]
                            - f1g[Q2][Q][ul] * f2g[P][vh];
                    acc[k] = MFMA32(a, b, acc[k]);
                }
            }
        }
    }
}

#define WAITN(N) asm volatile("s_waitcnt vmcnt(" #N ")" ::: "memory")
#define BAR()    __builtin_amdgcn_s_barrier()
#define PRIO1()  __builtin_amdgcn_s_setprio(1)
#define PRIO0()  __builtin_amdgcn_s_setprio(0)

__global__ __launch_bounds__(256, 3)
void tp_main(const float* __restrict__ x1, const float* __restrict__ x2,
             const f16* __restrict__ wsW, float* __restrict__ out)
{
    __shared__ __align__(16) f16 ldsW[3][8192];  // 48 KB: 3-buffer ring, 16 KB stages

    const int tid = threadIdx.x, lane = tid & 63, wv = tid >> 6;
    const int rowBase = blockIdx.x * 128 + wv * 32;
    const int mrow = lane & 31;          // this lane's row (A and C/D)
    const int half = lane >> 5;          // k-group
    const int klo = half * 8;
    const float4* x1r4 = (const float4*)(x1 + (size_t)(rowBase + mrow) * 128);
    const float4* x2r4 = (const float4*)(x2 + (size_t)(rowBase + mrow) * 128);

    // stage s (s in [0,20)): tensor c = s/4, quarter q = s%4, buffer s%3.
    auto issue = [&](int s) {
        const f16* src = wsW + s * 8192;
        f16* dst = &ldsW[s % 3][0];
#pragma unroll
        for (int it = 0; it < 4; ++it) {
            int o = (it * 256 + tid) * 8;
            __builtin_amdgcn_global_load_lds(
                (const __attribute__((address_space(1))) void*)(src + o),
                (__attribute__((address_space(3))) void*)(dst + o), 16, 0, 0);
        }
    };

    issue(0);  // stage 0 in flight during the whole prologue

    // ---- f1: all 128 features of my row, f16, [arr][u] ----
    f16x8 f1g[4][4];
    {
        float b0[32];
#pragma unroll
        for (int g = 0; g < 8; ++g) ((float4*)b0)[g] = x1r4[g];
#pragma unroll
        for (int g = 0; g < 4; ++g)
#pragma unroll
            for (int j = 0; j < 8; ++j) f1g[0][g][j] = (f16)b0[g * 8 + j];
        float b1[96];
#pragma unroll
        for (int g = 0; g < 24; ++g) ((float4*)b1)[g] = x1r4[8 + g];
#pragma unroll
        for (int i = 0; i < 3; ++i)
#pragma unroll
            for (int g = 0; g < 4; ++g)
#pragma unroll
                for (int j = 0; j < 8; ++j)
                    f1g[1 + i][g][j] = (f16)b1[3 * (g * 8 + j) + i];
    }

    // ---- f2: my row's k-slice: v = vh*16 + klo + j, [arr][vh] ----
    f16x8 f2g[4][2];
    {
        float c0[16];
#pragma unroll
        for (int g = 0; g < 2; ++g) ((float4*)c0)[g]     = x2r4[klo / 4 + g];
#pragma unroll
        for (int g = 0; g < 2; ++g) ((float4*)c0)[2 + g] = x2r4[4 + klo / 4 + g];
#pragma unroll
        for (int vh = 0; vh < 2; ++vh)
#pragma unroll
            for (int j = 0; j < 8; ++j) f2g[0][vh][j] = (f16)c0[vh * 8 + j];
        // vec spans: floats [32+3*klo, +24) and [80+3*klo, +24), both 16B-aligned
        float c1[48];
        const int base1 = (32 + 3 * klo) / 4;
#pragma unroll
        for (int g = 0; g < 6; ++g) ((float4*)c1)[g]     = x2r4[base1 + g];
#pragma unroll
        for (int g = 0; g < 6; ++g) ((float4*)c1)[6 + g] = x2r4[base1 + 12 + g];
#pragma unroll
        for (int i = 0; i < 3; ++i)
#pragma unroll
            for (int vh = 0; vh < 2; ++vh)
#pragma unroll
                for (int j = 0; j < 8; ++j)
                    f2g[1 + i][vh][j] = (f16)c1[vh * 24 + 3 * j + i];
    }

    issue(1);  // second prefetch right before the pipeline starts

    f32x16 acc0[1] = {};
    f32x16 acc1[3] = {};
    f32x16 acc2[3] = {};

    // ================= stages 0..7: c0 (mode 0) + c1 (mode 1) -> acc0 ======
    WAITN(4); BAR(); issue(2);
    PRIO1(); do_stage<0, 0>(acc0, ldsW[0], f1g, f2g, lane); PRIO0();
    WAITN(4); BAR(); issue(3);
    PRIO1(); do_stage<1, 0>(acc0, ldsW[1], f1g, f2g, lane); PRIO0();
    WAITN(4); BAR(); issue(4);
    PRIO1(); do_stage<2, 0>(acc0, ldsW[2], f1g, f2g, lane); PRIO0();
    WAITN(4); BAR(); issue(5);
    PRIO1(); do_stage<3, 0>(acc0, ldsW[0], f1g, f2g, lane); PRIO0();
    WAITN(4); BAR(); issue(6);
    PRIO1(); do_stage<0, 1>(acc0, ldsW[1], f1g, f2g, lane); PRIO0();
    WAITN(4); BAR(); issue(7);
    PRIO1(); do_stage<1, 1>(acc0, ldsW[2], f1g, f2g, lane); PRIO0();
    WAITN(4); BAR(); issue(8);
    PRIO1(); do_stage<2, 1>(acc0, ldsW[0], f1g, f2g, lane); PRIO0();
    WAITN(4); BAR(); issue(9);
    PRIO1(); do_stage<3, 1>(acc0, ldsW[1], f1g, f2g, lane); PRIO0();

    // ================= stages 8..15: c2 (mode 2) + c3 (mode 3) -> acc1 =====
    WAITN(4); BAR(); issue(10);
    {   // out0 stores overlap stage-8 compute; drained by the vmcnt(0) at s9
#pragma unroll
        for (int reg = 0; reg < 16; ++reg) {
            int r = (reg & 3) + 8 * (reg >> 2) + 4 * half;
            out[(size_t)(rowBase + r) * 224 + mrow] = acc0[0][reg];
        }
    }
    PRIO1(); do_stage<0, 2>(acc1, ldsW[2], f1g, f2g, lane); PRIO0();
    WAITN(0); BAR(); issue(11);   // vmcnt(0): store count unknown -> safe drain
    PRIO1(); do_stage<1, 2>(acc1, ldsW[0], f1g, f2g, lane); PRIO0();
    WAITN(4); BAR(); issue(12);
    PRIO1(); do_stage<2, 2>(acc1, ldsW[1], f1g, f2g, lane); PRIO0();
    WAITN(4); BAR(); issue(13);
    PRIO1(); do_stage<3, 2>(acc1, ldsW[2], f1g, f2g, lane); PRIO0();
    WAITN(4); BAR(); issue(14);
    PRIO1(); do_stage<0, 3>(acc1, ldsW[0], f1g, f2g, lane); PRIO0();
    WAITN(4); BAR(); issue(15);
    PRIO1(); do_stage<1, 3>(acc1, ldsW[1], f1g, f2g, lane); PRIO0();
    WAITN(4); BAR(); issue(16);
    PRIO1(); do_stage<2, 3>(acc1, ldsW[2], f1g, f2g, lane); PRIO0();
    WAITN(4); BAR(); issue(17);
    PRIO1(); do_stage<3, 3>(acc1, ldsW[0], f1g, f2g, lane); PRIO0();

    // ================= stages 16..19: c4 (mode 4) -> acc2 ==================
    WAITN(4); BAR(); issue(18);
    {   // out1 stores overlap stage-16 compute
#pragma unroll
        for (int reg = 0; reg < 16; ++reg) {
            int r = (reg & 3) + 8 * (reg >> 2) + 4 * half;
            size_t base = (size_t)(rowBase + r) * 224 + 32 + 3 * mrow;
            out[base + 0] = acc1[0][reg];
            out[base + 1] = acc1[1][reg];
            out[base + 2] = acc1[2][reg];
        }
    }
    PRIO1(); do_stage<0, 4>(acc2, ldsW[1], f1g, f2g, lane); PRIO0();
    WAITN(0); BAR(); issue(19);   // post-store safe drain
    PRIO1(); do_stage<1, 4>(acc2, ldsW[2], f1g, f2g, lane); PRIO0();
    WAITN(4); BAR();
    PRIO1(); do_stage<2, 4>(acc2, ldsW[0], f1g, f2g, lane); PRIO0();
    WAITN(0); BAR();
    PRIO1(); do_stage<3, 4>(acc2, ldsW[1], f1g, f2g, lane); PRIO0();

#pragma unroll
    for (int reg = 0; reg < 16; ++reg) {
        int r = (reg & 3) + 8 * (reg >> 2) + 4 * half;
        size_t base = (size_t)(rowBase + r) * 224 + 128 + 3 * mrow;
        out[base + 0] = acc2[0][reg];
        out[base + 1] = acc2[1][reg];
        out[base + 2] = acc2[2][reg];
    }
}

// ---------------- launch -----------------------------------------------------
extern "C" void kernel_launch(void* const* d_in, const int* in_sizes, int n_in,
                              void* d_out, int out_size, void* d_ws, size_t ws_size,
                              hipStream_t stream)
{
    const float* x1   = (const float*)d_in[0];
    const float* x2   = (const float*)d_in[1];
    const float* w000 = (const float*)d_in[2];
    const float* w011 = (const float*)d_in[3];
    const float* w101 = (const float*)d_in[4];
    const float* w110 = (const float*)d_in[5];
    const float* w111 = (const float*)d_in[6];
    float* out = (float*)d_out;
    f16* wsW = (f16*)d_ws;  // 5 * 32768 f16 = 320 KB

    hipLaunchKernelGGL(prep_w, dim3(640), dim3(256), 0, stream,
                       w000, w011, w101, w110, w111, wsW);

    int n = in_sizes[0] / 128;  // 131072 rows
    hipLaunchKernelGGL(tp_main, dim3(n / 128), dim3(256), 0, stream,
                       x1, x2, wsW, out);
}

// Round 4
// 284.860 us; speedup vs baseline: 1.2757x; 1.1455x over previous
//
#include <hip/hip_runtime.h>

// e3nn fully-connected tensor product, v7: v4's proven geometry (32 KB stages,
// 2-buffer 64 KB LDS, 2 blocks/CU, section-lived accumulators) with ONLY the
// sync structure changed: raw s_barrier + counted s_waitcnt vmcnt(N) instead
// of __syncthreads(), so the next-stage prefetch stays in flight across the
// barrier (v4's __syncthreads emitted vmcnt(0), draining the just-issued
// prefetch every stage -> the ~37% idle the counters showed).
// Per stage:  WAITN(N); BAR;  [stores]; compute(buf s&1); BAR; issue(s+2)
//   - loads-landed: WAITN retires issue(s) (own wave) + BAR (other waves)
//   - WAR: issue(s+2) overwrites buf s&1 only after all waves' ds_reads were
//     consumed (lgkm-waited before their MFMAs, which precede the 2nd BAR)
//   - vmcnt retires IN ORDER, so N = min #vmcnt-ops guaranteed issued after
//     the target load: 8 steady-state, 24 after the 16-dword out0 burst,
//     16 after the out1 burst (>=16 ops even if merged to dwordx3).

typedef _Float16 f16;
typedef f16 f16x8 __attribute__((ext_vector_type(8)));
typedef float f32x16 __attribute__((ext_vector_type(16)));

#define MFMA32(a, b, c) __builtin_amdgcn_mfma_f32_32x32x16_f16(a, b, c, 0, 0, 0)

// A000 = A011 = A101 = A111 = 1/sqrt(2048); A110 = 1/sqrt(6144)
#define SC_COMMON 0.022097086912079608f
#define SC_110    0.012757759118834242f

// ---------------- weight prep ------------------------------------------------
// ws order: c0=w000, c1=w110, c2=w011, c3=w101, c4=w111 (scales folded).
// B-frag (32x32x16): lane holds B[k=(lane>>5)*8+j][n=lane&31], K-chunk vh.
// idx = ((c*32 + u)*2 + vh)*512 + lane*8 + j
//   element = sc * W[u][ v = vh*16 + (lane>>5)*8 + j ][ w = lane&31 ]
__global__ void prep_w(const float* __restrict__ w000, const float* __restrict__ w011,
                       const float* __restrict__ w101, const float* __restrict__ w110,
                       const float* __restrict__ w111, f16* __restrict__ wsW)
{
    int flat = blockIdx.x * 256 + threadIdx.x;
    if (flat >= 5 * 32768) return;
    int c    = flat >> 15;
    int r    = flat & 32767;
    int j    = r & 7;
    int lane = (r >> 3) & 63;
    int vh   = (r >> 9) & 1;
    int u    = r >> 10;
    int v = vh * 16 + ((lane >> 5) << 3) + j;
    int w = lane & 31;
    const float* src; float sc;
    switch (c) {
        case 0: src = w000; sc = SC_COMMON; break;
        case 1: src = w110; sc = SC_110;    break;
        case 2: src = w011; sc = SC_COMMON; break;
        case 3: src = w101; sc = SC_COMMON; break;
        default: src = w111; sc = SC_COMMON; break;
    }
    wsW[flat] = (f16)(sc * src[u * 1024 + v * 32 + w]);
}

// ---------------- stage compute ---------------------------------------------
// One stage = 16 u-values (half-tensor, U0 in {0,16}) x 2 vh chunks.
// MODE: 0 = w000 (s*s), 1 = w110 (vec dot), 2 = w011 (p011, 3 acc),
//       3 = w101 (p101, 3 acc), 4 = w111 (cross, 3 acc)
template <int U0, int MODE, int NA>
__device__ __forceinline__ void do_stage(f32x16 (&acc)[NA],
                                         const f16* __restrict__ ldsW,
                                         const f16x8 (&f1g)[4][4],
                                         const f16x8 (&f2g)[4][2], int lane)
{
#pragma unroll
    for (int ul = 0; ul < 16; ++ul) {
        const int u = U0 + ul;
#pragma unroll
        for (int vh = 0; vh < 2; ++vh) {
            f16x8 b = *(const f16x8*)(ldsW + ul * 1024 + vh * 512 + lane * 8);
            if (MODE == 0) {
                f16x8 a = f1g[0][u >> 3][u & 7] * f2g[0][vh];
                acc[0] = MFMA32(a, b, acc[0]);
            } else if (MODE == 1) {
                f16x8 a = f1g[1][u >> 3][u & 7] * f2g[1][vh];
                a += f1g[2][u >> 3][u & 7] * f2g[2][vh];
                a += f1g[3][u >> 3][u & 7] * f2g[3][vh];
                acc[0] = MFMA32(a, b, acc[0]);
            } else if (MODE == 2) {
#pragma unroll
                for (int j = 0; j < 3; ++j) {
                    f16x8 a = f1g[0][u >> 3][u & 7] * f2g[1 + j][vh];
                    acc[j] = MFMA32(a, b, acc[j]);
                }
            } else if (MODE == 3) {
#pragma unroll
                for (int j = 0; j < 3; ++j) {
                    f16x8 a = f1g[1 + j][u >> 3][u & 7] * f2g[0][vh];
                    acc[j] = MFMA32(a, b, acc[j]);
                }
            } else {
                // cross: k0:(i=1,j=2)->arrs(2,3); k1:(2,0)->(3,1); k2:(0,1)->(1,2)
#pragma unroll
                for (int k = 0; k < 3; ++k) {
                    const int P = (k == 0) ? 2 : (k == 1) ? 3 : 1;
                    const int Q = (k == 0) ? 3 : (k == 1) ? 1 : 2;
                    f16x8 a = f1g[P][u >> 3][u & 7] * f2g[Q][vh]
                            - f1g[Q][u >> 3][u & 7] * f2g[P][vh];
                    acc[k] = MFMA32(a, b, acc[k]);
                }
            }
        }
    }
}

#define WAITN(N) asm volatile("s_waitcnt vmcnt(" #N ")" ::: "memory")
#define BAR()    __builtin_amdgcn_s_barrier()
#define PRIO1()  __builtin_amdgcn_s_setprio(1)
#define PRIO0()  __builtin_amdgcn_s_setprio(0)

__global__ __launch_bounds__(256, 2)
void tp_main(const float* __restrict__ x1, const float* __restrict__ x2,
             const f16* __restrict__ wsW, float* __restrict__ out)
{
    __shared__ __align__(16) f16 ldsW[2][16384];  // 64 KB, 2-buffer, 32 KB stages

    const int tid = threadIdx.x, lane = tid & 63, wv = tid >> 6;
    const int rowBase = blockIdx.x * 128 + wv * 32;
    const int mrow = lane & 31;          // this lane's row (A and C/D)
    const int half = lane >> 5;          // k-group
    const int klo = half * 8;
    const float4* x1r4 = (const float4*)(x1 + (size_t)(rowBase + mrow) * 128);
    const float4* x2r4 = (const float4*)(x2 + (size_t)(rowBase + mrow) * 128);

    // stage s in [0,10): tensor c = s/2, half h = s&1, buffer s&1.
    auto issue = [&](int s) {
        const f16* src = wsW + (size_t)s * 16384;
        f16* dst = &ldsW[s & 1][0];
#pragma unroll
        for (int it = 0; it < 8; ++it) {
            int o = (it * 256 + tid) * 8;
            __builtin_amdgcn_global_load_lds(
                (const __attribute__((address_space(1))) void*)(src + o),
                (__attribute__((address_space(3))) void*)(dst + o), 16, 0, 0);
        }
    };

    issue(0);  // stage 0 DMA in flight during the whole prologue

    // ---- f1: all 128 features of my row, f16, [arr][u] ----
    f16x8 f1g[4][4];
    {
        float b0[32];
#pragma unroll
        for (int g = 0; g < 8; ++g) ((float4*)b0)[g] = x1r4[g];
#pragma unroll
        for (int g = 0; g < 4; ++g)
#pragma unroll
            for (int j = 0; j < 8; ++j) f1g[0][g][j] = (f16)b0[g * 8 + j];
        float b1[96];
#pragma unroll
        for (int g = 0; g < 24; ++g) ((float4*)b1)[g] = x1r4[8 + g];
#pragma unroll
        for (int i = 0; i < 3; ++i)
#pragma unroll
            for (int g = 0; g < 4; ++g)
#pragma unroll
                for (int j = 0; j < 8; ++j)
                    f1g[1 + i][g][j] = (f16)b1[3 * (g * 8 + j) + i];
    }

    // ---- f2: my row's k-slice: v = vh*16 + klo + j, [arr][vh] ----
    f16x8 f2g[4][2];
    {
        float c0[16];
#pragma unroll
        for (int g = 0; g < 2; ++g) ((float4*)c0)[g]     = x2r4[klo / 4 + g];
#pragma unroll
        for (int g = 0; g < 2; ++g) ((float4*)c0)[2 + g] = x2r4[4 + klo / 4 + g];
#pragma unroll
        for (int vh = 0; vh < 2; ++vh)
#pragma unroll
            for (int j = 0; j < 8; ++j) f2g[0][vh][j] = (f16)c0[vh * 8 + j];
        // vec spans: floats [32+3*klo, +24) and [80+3*klo, +24), both 16B-aligned
        float c1[48];
        const int base1 = (32 + 3 * klo) / 4;
#pragma unroll
        for (int g = 0; g < 6; ++g) ((float4*)c1)[g]     = x2r4[base1 + g];
#pragma unroll
        for (int g = 0; g < 6; ++g) ((float4*)c1)[6 + g] = x2r4[base1 + 12 + g];
#pragma unroll
        for (int i = 0; i < 3; ++i)
#pragma unroll
            for (int vh = 0; vh < 2; ++vh)
#pragma unroll
                for (int j = 0; j < 8; ++j)
                    f2g[1 + i][vh][j] = (f16)c1[vh * 24 + 3 * j + i];
    }

    issue(1);  // second prefetch right before the pipeline starts

    f32x16 acc0[1] = {};
    f32x16 acc1[3] = {};
    f32x16 acc2[3] = {};

    // ---- stage 0: c0 h0, mode 0 -> acc0 ----
    WAITN(8); BAR();
    PRIO1(); do_stage<0, 0>(acc0, ldsW[0], f1g, f2g, lane); PRIO0();
    BAR(); issue(2);
    // ---- stage 1: c0 h1 ----
    WAITN(8); BAR();
    PRIO1(); do_stage<16, 0>(acc0, ldsW[1], f1g, f2g, lane); PRIO0();
    BAR(); issue(3);
    // ---- stage 2: c1 h0, mode 1 ----
    WAITN(8); BAR();
    PRIO1(); do_stage<0, 1>(acc0, ldsW[0], f1g, f2g, lane); PRIO0();
    BAR(); issue(4);
    // ---- stage 3: c1 h1 ----
    WAITN(8); BAR();
    PRIO1(); do_stage<16, 1>(acc0, ldsW[1], f1g, f2g, lane); PRIO0();
    BAR(); issue(5);
    // ---- stage 4: c2 h0, mode 2 -> acc1; out0 stores overlap compute ----
    WAITN(8); BAR();
#pragma unroll
    for (int reg = 0; reg < 16; ++reg) {
        int r = (reg & 3) + 8 * (reg >> 2) + 4 * half;
        out[(size_t)(rowBase + r) * 224 + mrow] = acc0[0][reg];  // 16 dword stores
    }
    PRIO1(); do_stage<0, 2>(acc1, ldsW[0], f1g, f2g, lane); PRIO0();
    BAR(); issue(6);
    // ---- stage 5: c2 h1 (16 stores + issue(6) are newer than issue(5)) ----
    WAITN(24); BAR();
    PRIO1(); do_stage<16, 2>(acc1, ldsW[1], f1g, f2g, lane); PRIO0();
    BAR(); issue(7);
    // ---- stage 6: c3 h0, mode 3 ----
    WAITN(8); BAR();
    PRIO1(); do_stage<0, 3>(acc1, ldsW[0], f1g, f2g, lane); PRIO0();
    BAR(); issue(8);
    // ---- stage 7: c3 h1 ----
    WAITN(8); BAR();
    PRIO1(); do_stage<16, 3>(acc1, ldsW[1], f1g, f2g, lane); PRIO0();
    BAR(); issue(9);
    // ---- stage 8: c4 h0, mode 4 -> acc2; out1 stores overlap compute ----
    WAITN(8); BAR();
#pragma unroll
    for (int reg = 0; reg < 16; ++reg) {
        int r = (reg & 3) + 8 * (reg >> 2) + 4 * half;
        size_t base = (size_t)(rowBase + r) * 224 + 32 + 3 * mrow;
        out[base + 0] = acc1[0][reg];
        out[base + 1] = acc1[1][reg];
        out[base + 2] = acc1[2][reg];   // >=16 vmcnt ops even if merged
    }
    PRIO1(); do_stage<0, 4>(acc2, ldsW[0], f1g, f2g, lane); PRIO0();
    BAR();
    // ---- stage 9: c4 h1 (out1 stores are newer than issue(9)) ----
    WAITN(16); BAR();
    PRIO1(); do_stage<16, 4>(acc2, ldsW[1], f1g, f2g, lane); PRIO0();

#pragma unroll
    for (int reg = 0; reg < 16; ++reg) {
        int r = (reg & 3) + 8 * (reg >> 2) + 4 * half;
        size_t base = (size_t)(rowBase + r) * 224 + 128 + 3 * mrow;
        out[base + 0] = acc2[0][reg];
        out[base + 1] = acc2[1][reg];
        out[base + 2] = acc2[2][reg];
    }
}

// ---------------- launch -----------------------------------------------------
extern "C" void kernel_launch(void* const* d_in, const int* in_sizes, int n_in,
                              void* d_out, int out_size, void* d_ws, size_t ws_size,
                              hipStream_t stream)
{
    const float* x1   = (const float*)d_in[0];
    const float* x2   = (const float*)d_in[1];
    const float* w000 = (const float*)d_in[2];
    const float* w011 = (const float*)d_in[3];
    const float* w101 = (const float*)d_in[4];
    const float* w110 = (const float*)d_in[5];
    const float* w111 = (const float*)d_in[6];
    float* out = (float*)d_out;
    f16* wsW = (f16*)d_ws;  // 5 * 32768 f16 = 320 KB

    hipLaunchKernelGGL(prep_w, dim3(640), dim3(256), 0, stream,
                       w000, w011, w101, w110, w111, wsW);

    int n = in_sizes[0] / 128;  // 131072 rows
    hipLaunchKernelGGL(tp_main, dim3(n / 128), dim3(256), 0, stream,
                       x1, x2, wsW, out);
}